// Round 6
// baseline (297.796 us; speedup 1.0000x reference)
//
#include <hip/hip_runtime.h>

// Euler-Maruyama prefix-product, float4, 2 rows/block, pipelined phases.
//   Z[b,i] = Z0[b] * prod_{j=1..i} (1 + r*dt + s*sqrt(dt)*W[b,j])
// Phases: (1) load BOTH rows' W as aligned float4 + compute multipliers +
// EARLY W-copy/head stores (stores overlap the scan), (2) two independent
// wave product-scans (ILP on DS pipe), (3) one __syncthreads for both rows'
// wave totals, (4) cross-wave combine + coalesced float4 Z stores.
// Rows start at base+1 ((r+1)&3 misaligned): block-uniform scalar head
// (folded into carry, stored early) + aligned body + <=3-scalar tail (t=255).
// XCD-chunked pair swizzle keeps adjacent rows in one XCD's L2.
// Output tuple (Z, W): d_out = [Z (B*1025 f32), verbatim W copy].

__global__ __launch_bounds__(256, 8) void em_f4x2_kernel(
    const float* __restrict__ Z0,
    const float* __restrict__ W,
    const float* __restrict__ Wf,
    const float* __restrict__ Wg,
    float* __restrict__ Zout,
    float* __restrict__ Wout,
    int B)
{
    constexpr int NP1 = 1025;
    const int t    = threadIdx.x;
    const int lane = t & 63;
    const int wid  = t >> 6;

    // Row-pair index, XCD-chunked bijective swizzle (8 XCDs, P % 8 == 0).
    const int P   = B >> 1;
    const int npx = P >> 3;
    const int bid = (int)blockIdx.x;
    const int q   = (bid & 7) * npx + (bid >> 3);
    const int r0  = q << 1;

    const float dt  = 1.0f / 1024.0f;   // exact
    const float sdt = 0.03125f;         // sqrt(1/1024), exact
    const float a   = Wf[0] * dt;
    const float c   = Wg[0] * sdt;
    const float m0  = 1.0f + a;

    __shared__ float wtot[2][4];

    float m[2][4];                 // per-thread multipliers, both rows
    float pincl[2];                // inclusive wave-scan results
    float z0v[2], headprod[2];
    int   hh[2], nvv[2], i0v[2], tlv[2];

    // ---- Phase 1: loads + multipliers + early W-copy/head stores ----
    #pragma unroll
    for (int j = 0; j < 2; ++j) {
        const int r = r0 + j;
        const size_t base = (size_t)r * NP1;
        const float* __restrict__ wrow  = W    + base;
        float*       __restrict__ worow = Wout + base;
        float*       __restrict__ zrow  = Zout + base;

        const int h  = (4 - ((r + 1) & 3)) & 3;  // scalar head count
        const int nv = (1024 - h) >> 2;          // full float4s (256 or 255)
        const int i0 = 1 + h + (nv << 2);        // first tail row-index
        const int tl = 1024 - h - (nv << 2);     // tail count (0 or 4-h)
        hh[j] = h; nvv[j] = nv; i0v[j] = i0; tlv[j] = tl;

        float wh0 = 0.f, wh1 = 0.f, wh2 = 0.f;
        if (h > 0) wh0 = wrow[1];
        if (h > 1) wh1 = wrow[2];
        if (h > 2) wh2 = wrow[3];

        float mm0 = 1.f, mm1 = 1.f, mm2 = 1.f, mm3 = 1.f;
        if (t < nv) {
            const float4* __restrict__ wv =
                reinterpret_cast<const float4*>(wrow + 1 + h);
            float4 wq = wv[t];
            mm0 = fmaf(c, wq.x, m0);
            mm1 = fmaf(c, wq.y, m0);
            mm2 = fmaf(c, wq.z, m0);
            mm3 = fmaf(c, wq.w, m0);
            float4* __restrict__ wov =
                reinterpret_cast<float4*>(worow + 1 + h);
            wov[t] = wq;                          // EARLY W-copy store
        } else {                                  // only t==255 when h>0
            if (tl > 0) { float tw = wrow[i0+0]; mm0 = fmaf(c, tw, m0); worow[i0+0] = tw; }
            if (tl > 1) { float tw = wrow[i0+1]; mm1 = fmaf(c, tw, m0); worow[i0+1] = tw; }
            if (tl > 2) { float tw = wrow[i0+2]; mm2 = fmaf(c, tw, m0); worow[i0+2] = tw; }
        }

        const float z0 = Z0[r];                   // block-uniform
        float hp = 1.0f;
        if (h > 0) hp *= fmaf(c, wh0, m0);
        if (h > 1) hp *= fmaf(c, wh1, m0);
        if (h > 2) hp *= fmaf(c, wh2, m0);

        if (t == 0) {                             // head outputs, scan-free
            zrow[0]  = z0;
            worow[0] = wrow[0];
            float run = z0;
            if (h > 0) { run *= fmaf(c, wh0, m0); zrow[1] = run; worow[1] = wh0; }
            if (h > 1) { run *= fmaf(c, wh1, m0); zrow[2] = run; worow[2] = wh1; }
            if (h > 2) { run *= fmaf(c, wh2, m0); zrow[3] = run; worow[3] = wh2; }
        }

        m[j][0] = mm0; m[j][1] = mm1; m[j][2] = mm2; m[j][3] = mm3;
        z0v[j] = z0; headprod[j] = hp;
    }

    // ---- Phase 2: two independent wave-level inclusive product scans ----
    #pragma unroll
    for (int j = 0; j < 2; ++j) {
        float p = (m[j][0] * m[j][1]) * (m[j][2] * m[j][3]);
        #pragma unroll
        for (int d = 1; d < 64; d <<= 1) {
            float o = __shfl_up(p, d, 64);
            if (lane >= d) p *= o;
        }
        pincl[j] = p;
        if (lane == 63) wtot[j][wid] = p;
    }

    // ---- Phase 3: single barrier for both rows ----
    __syncthreads();

    // ---- Phase 4: cross-wave combine + coalesced Z stores ----
    #pragma unroll
    for (int j = 0; j < 2; ++j) {
        const int r = r0 + j;
        const size_t base = (size_t)r * NP1;
        float* __restrict__ zrow = Zout + base;

        float ep = __shfl_up(pincl[j], 1, 64);
        if (lane == 0) ep = 1.0f;
        float wpre = 1.0f;
        if (wid > 0) wpre *= wtot[j][0];
        if (wid > 1) wpre *= wtot[j][1];
        if (wid > 2) wpre *= wtot[j][2];

        const float S = ((z0v[j] * headprod[j]) * wpre) * ep;
        const int h = hh[j], nv = nvv[j], i0 = i0v[j], tl = tlv[j];

        if (t < nv) {
            float zx = S  * m[j][0];
            float zy = zx * m[j][1];
            float zz = zy * m[j][2];
            float zw = zz * m[j][3];
            float4* __restrict__ zv = reinterpret_cast<float4*>(zrow + 1 + h);
            zv[t] = make_float4(zx, zy, zz, zw);
        } else {
            float run = S;
            if (tl > 0) { run *= m[j][0]; zrow[i0 + 0] = run; }
            if (tl > 1) { run *= m[j][1]; zrow[i0 + 1] = run; }
            if (tl > 2) { run *= m[j][2]; zrow[i0 + 2] = run; }
        }
    }
}

extern "C" void kernel_launch(void* const* d_in, const int* in_sizes, int n_in,
                              void* d_out, int out_size, void* d_ws, size_t ws_size,
                              hipStream_t stream) {
    const float* Z0 = (const float*)d_in[0];
    const float* W  = (const float*)d_in[1];
    const float* Wf = (const float*)d_in[2];
    const float* Wg = (const float*)d_in[3];

    const int B   = in_sizes[0];              // 131072
    const int NP1 = in_sizes[1] / B;          // 1025
    (void)NP1;

    float* Zout = (float*)d_out;
    float* Wout = Zout + (size_t)B * 1025;

    const int blocks = B >> 1;                // 2 rows per block
    em_f4x2_kernel<<<blocks, 256, 0, stream>>>(Z0, W, Wf, Wg, Zout, Wout, B);
}

// Round 8
// 289.237 us; speedup vs baseline: 1.0296x; 1.0296x over previous
//
#include <hip/hip_runtime.h>

// Euler-Maruyama prefix-product, float4 edition + nontemporal body stores.
//   Z[b,i] = Z0[b] * prod_{j=1..i} (1 + r*dt + s*sqrt(dt)*W[b,j])
// One 256-thread block per row. Thread t owns 4 CONTIGUOUS elements
// (aligned float4 #t of the row body): local serial product, wave scan over
// 256 per-thread products (6 shfls) + LDS cross-wave combine. All bulk
// loads/stores are aligned float4. Body stores are NONTEMPORAL (write-once
// streams should not allocate in L2 and evict the W read stream) — via a
// native ext_vector float4 (HIP_vector_type is rejected by the builtin).
// Rows start at base+1 ((r+1)&3 misaligned): block-uniform scalar head
// (folded into carry) + aligned body + <=3-scalar tail on thread 255.
// XCD-chunked row swizzle keeps row-boundary cache lines in one L2.
// Output tuple (Z, W): d_out = [Z (B*1025 f32), verbatim W copy].

typedef float f32x4 __attribute__((ext_vector_type(4)));

__global__ __launch_bounds__(256) void em_f4nt_kernel(
    const float* __restrict__ Z0,
    const float* __restrict__ W,
    const float* __restrict__ Wf,
    const float* __restrict__ Wg,
    float* __restrict__ Zout,
    float* __restrict__ Wout,
    int B)
{
    constexpr int NP1 = 1025;
    const int t    = threadIdx.x;
    const int lane = t & 63;
    const int wid  = t >> 6;

    // XCD-chunked bijective swizzle (8 XCDs, B % 8 == 0).
    const int nper = B >> 3;
    const int bid  = (int)blockIdx.x;
    const int r    = (bid & 7) * nper + (bid >> 3);

    const float dt  = 1.0f / 1024.0f;   // exact
    const float sdt = 0.03125f;         // sqrt(1/1024), exact
    const float a   = Wf[0] * dt;
    const float c   = Wg[0] * sdt;
    const float m0  = 1.0f + a;

    const size_t base = (size_t)r * NP1;
    const float* __restrict__ wrow  = W    + base;
    float*       __restrict__ zrow  = Zout + base;
    float*       __restrict__ worow = Wout + base;

    // Row scan body = indices 1..1024. (base+1) % 4 == (r+1) & 3.
    const int h    = (4 - ((r + 1) & 3)) & 3;  // scalar head count (0..3)
    const int nv   = (1024 - h) >> 2;          // full float4s: 256 (h==0) or 255
    const int tail = 1024 - h - (nv << 2);     // 0 (h==0) or 4-h

    // Head multipliers (row idx 1..h), block-uniform broadcast loads.
    float wh0 = 0.f, wh1 = 0.f, wh2 = 0.f;
    float headprod = 1.0f;
    if (h > 0) { wh0 = wrow[1]; headprod *= fmaf(c, wh0, m0); }
    if (h > 1) { wh1 = wrow[2]; headprod *= fmaf(c, wh1, m0); }
    if (h > 2) { wh2 = wrow[3]; headprod *= fmaf(c, wh2, m0); }

    const bool isvec = (t < nv);
    f32x4 wq = (f32x4)(0.f);
    float tw0 = 0.f, tw1 = 0.f, tw2 = 0.f;
    float m1 = 1.f, m2 = 1.f, m3 = 1.f, m4 = 1.f;
    const int i0 = 1 + h + (nv << 2);          // first tail row-index
    if (isvec) {
        const f32x4* __restrict__ wv =
            reinterpret_cast<const f32x4*>(wrow + 1 + h);
        wq = wv[t];
        m1 = fmaf(c, wq.x, m0);
        m2 = fmaf(c, wq.y, m0);
        m3 = fmaf(c, wq.z, m0);
        m4 = fmaf(c, wq.w, m0);
    } else {
        if (tail > 0) { tw0 = wrow[i0 + 0]; m1 = fmaf(c, tw0, m0); }
        if (tail > 1) { tw1 = wrow[i0 + 1]; m2 = fmaf(c, tw1, m0); }
        if (tail > 2) { tw2 = wrow[i0 + 2]; m3 = fmaf(c, tw2, m0); }
    }
    float prod = (m1 * m2) * (m3 * m4);

    // Wave-level inclusive scan over the 256 per-thread products.
    float p = prod;
    #pragma unroll
    for (int d = 1; d < 64; d <<= 1) {
        float o = __shfl_up(p, d, 64);
        if (lane >= d) p *= o;
    }

    __shared__ float wtot[4];
    if (lane == 63) wtot[wid] = p;
    __syncthreads();

    // Exclusive-within-wave + cross-wave prefix.
    float ep = __shfl_up(p, 1, 64);
    if (lane == 0) ep = 1.0f;
    float wpre = 1.0f;
    if (wid > 0) wpre *= wtot[0];
    if (wid > 1) wpre *= wtot[1];
    if (wid > 2) wpre *= wtot[2];

    const float z0 = Z0[r];                    // block-uniform -> scalar load

    if (t == 0) {
        zrow[0]  = z0;
        worow[0] = wrow[0];                    // W[:,0] copy
        float run = z0;
        if (h > 0) { run *= fmaf(c, wh0, m0); zrow[1] = run; worow[1] = wh0; }
        if (h > 1) { run *= fmaf(c, wh1, m0); zrow[2] = run; worow[2] = wh1; }
        if (h > 2) { run *= fmaf(c, wh2, m0); zrow[3] = run; worow[3] = wh2; }
    }

    // S = product of everything strictly before this thread's first element.
    const float S = ((z0 * headprod) * wpre) * ep;

    if (isvec) {
        float zx = S  * m1;
        float zy = zx * m2;
        float zz = zy * m3;
        float zw = zz * m4;
        f32x4 zq; zq.x = zx; zq.y = zy; zq.z = zz; zq.w = zw;
        f32x4* __restrict__ zv  = reinterpret_cast<f32x4*>(zrow  + 1 + h);
        f32x4* __restrict__ wov = reinterpret_cast<f32x4*>(worow + 1 + h);
        __builtin_nontemporal_store(zq, zv + t);
        __builtin_nontemporal_store(wq, wov + t);
    } else {
        float run = S;
        if (tail > 0) { run *= m1; zrow[i0 + 0] = run; worow[i0 + 0] = tw0; }
        if (tail > 1) { run *= m2; zrow[i0 + 1] = run; worow[i0 + 1] = tw1; }
        if (tail > 2) { run *= m3; zrow[i0 + 2] = run; worow[i0 + 2] = tw2; }
    }
}

extern "C" void kernel_launch(void* const* d_in, const int* in_sizes, int n_in,
                              void* d_out, int out_size, void* d_ws, size_t ws_size,
                              hipStream_t stream) {
    const float* Z0 = (const float*)d_in[0];
    const float* W  = (const float*)d_in[1];
    const float* Wf = (const float*)d_in[2];
    const float* Wg = (const float*)d_in[3];

    const int B   = in_sizes[0];              // 131072
    const int NP1 = in_sizes[1] / B;          // 1025
    (void)NP1;

    float* Zout = (float*)d_out;
    float* Wout = Zout + (size_t)B * 1025;

    em_f4nt_kernel<<<B, 256, 0, stream>>>(Z0, W, Wf, Wg, Zout, Wout, B);
}